// Round 4
// baseline (398.111 us; speedup 1.0000x reference)
//
#include <hip/hip_runtime.h>
#include <hip/hip_bf16.h>

typedef __bf16 bf16x8 __attribute__((ext_vector_type(8)));
typedef __bf16 bf16x2 __attribute__((ext_vector_type(2)));
typedef float f32x4 __attribute__((ext_vector_type(4)));

#define NROWS 100000
#define NSTRIPS 6250   // 100000 / 16, exact
#define EPS 1e-5f
#define SLOPE 0.2f
#define INVN 1e-5f     // 1.0f / 100000

__device__ __forceinline__ bf16x8 cvt8(const float* s) {
    float4 x0 = *(const float4*)s, x1 = *(const float4*)(s + 4);
    bf16x8 o;
    o[0] = (__bf16)x0.x; o[1] = (__bf16)x0.y; o[2] = (__bf16)x0.z; o[3] = (__bf16)x0.w;
    o[4] = (__bf16)x1.x; o[5] = (__bf16)x1.y; o[6] = (__bf16)x1.z; o[7] = (__bf16)x1.w;
    return o;
}

// ---- streaming GEMM: Y = LeakyReLU(A @ W^T + bias), + column sum/sumsq --------
// Round-4 diagnosis: VGPR_Count stayed 40 even with a 128-reg cap (round 3) --
// the compiler SINKS the loop-invariant W-fragment loads into the strip loop
// (remat) in every configuration tried. bfrag(32)+afrag(16)+acc(8) can't live
// in 40 regs. The per-iteration serial chain is therefore
// {W-reload from L1 -> cvt -> MFMA} x KS*NI, ~5k cycles, which neither
// occupancy (r3) nor A-prefetch (r1) could hide. "W in registers" never held.
// Round-4 change (single variable): PIN the W-fragments with an empty inline
// asm "+v" after the init loads. The frag's def becomes the asm output, which
// cannot be rematerialized -> true register residency. Reg caps sized to fit:
//   gemm1  KT=128 NI=2: ~75 regs, bounds(256,5) cap 102, 20 waves/CU
//   gemm2/3 KT=256 NI=2: ~125 regs, bounds(256,3) cap 170, 12 waves/CU
// Falsifiable check: VGPR_Count must jump (40 -> 75+/120+). If not, pin failed
// and next step is the LDS-staged classic GEMM structure.
// A-frag: lane reads A[row0+l16][ks*32+quad*8 ..+8]. C/D: col=l16, row=quad*4+r.
template <int KT, int NI, int WAVES, int MINW, int NTOT, bool F32IN>
__global__ __launch_bounds__(WAVES * 64, MINW)
void gemm_stream(const __bf16* __restrict__ A, const float* __restrict__ A32,
                 const __bf16* __restrict__ W, const float* __restrict__ W32,
                 const float* __restrict__ bias, __bf16* __restrict__ Y,
                 float* __restrict__ sum, float* __restrict__ sumsq)
{
    constexpr int KS = KT / 32;
    const int wave = threadIdx.x >> 6, lane = threadIdx.x & 63;
    const int quad = lane >> 4, l16 = lane & 15;
    const int c0 = blockIdx.y * (NI * 16 * WAVES) + wave * (NI * 16);

    // W-fragments for this wave's column slice, full K, in registers
    bf16x8 bfrag[NI][KS];
    float bcol[NI];
    #pragma unroll
    for (int ni = 0; ni < NI; ++ni) {
        int col = c0 + ni * 16 + l16;
        bcol[ni] = bias[col];
        #pragma unroll
        for (int ks = 0; ks < KS; ++ks) {
            int k = ks * 32 + quad * 8;
            if constexpr (F32IN) bfrag[ni][ks] = cvt8(W32 + (size_t)col * KT + k);
            else                 bfrag[ni][ks] = *(const bf16x8*)(W + (size_t)col * KT + k);
        }
    }
    // PIN: force the W-fragments (and bias) to be materialized in VGPRs here.
    // The asm is the new def of each value -> the loads above cannot be
    // rematerialized inside the loop.
    #pragma unroll
    for (int ni = 0; ni < NI; ++ni) {
        asm volatile("" : "+v"(bcol[ni]));
        #pragma unroll
        for (int ks = 0; ks < KS; ++ks)
            asm volatile("" : "+v"(*reinterpret_cast<f32x4*>(&bfrag[ni][ks])));
    }

    float csum[NI] = {}, csq[NI] = {};

    for (int s = blockIdx.x; s < NSTRIPS; s += gridDim.x) {
        int row0 = s * 16;
        bf16x8 afrag[KS];
        #pragma unroll
        for (int ks = 0; ks < KS; ++ks) {
            int k = ks * 32 + quad * 8;
            if constexpr (F32IN) afrag[ks] = cvt8(A32 + (size_t)(row0 + l16) * KT + k);
            else                 afrag[ks] = *(const bf16x8*)(A + (size_t)(row0 + l16) * KT + k);
        }
        f32x4 acc[NI] = {};
        #pragma unroll
        for (int ks = 0; ks < KS; ++ks)
            #pragma unroll
            for (int ni = 0; ni < NI; ++ni)
                acc[ni] = __builtin_amdgcn_mfma_f32_16x16x32_bf16(
                    afrag[ks], bfrag[ni][ks], acc[ni], 0, 0, 0);

        #pragma unroll
        for (int ni = 0; ni < NI; ++ni) {
            int col = c0 + ni * 16 + l16;
            #pragma unroll
            for (int r = 0; r < 4; ++r) {
                float y = acc[ni][r] + bcol[ni];
                y = (y > 0.f) ? y : SLOPE * y;
                Y[(size_t)(row0 + quad * 4 + r) * NTOT + col] = (__bf16)y;
                csum[ni] += y;
                csq[ni]  += y * y;
            }
        }
    }

    #pragma unroll
    for (int ni = 0; ni < NI; ++ni) {
        float s = csum[ni], q = csq[ni];
        s += __shfl_xor(s, 16); s += __shfl_xor(s, 32);
        q += __shfl_xor(q, 16); q += __shfl_xor(q, 32);
        if (quad == 0) {
            int col = c0 + ni * 16 + l16;
            atomicAdd(&sum[col], s);
            atomicAdd(&sumsq[col], q);
        }
    }
}

// ---- fused stats + fold: every block recomputes s,t from column sums (cheap),
// then folds BN into the next layer: W' = W*diag(s) (bf16), b' = b + W@t.
__global__ void fold_stats_k(const float* __restrict__ sum, const float* __restrict__ sumsq,
                             const float* __restrict__ g, const float* __restrict__ beta,
                             const float* __restrict__ W, const float* __restrict__ b,
                             __bf16* __restrict__ Wf, float* __restrict__ bf_, int K)
{
    __shared__ float s_sh[256], t_sh[256];
    const int n = blockIdx.x, lane = threadIdx.x;  // 64 threads = 1 wave
    for (int k = lane; k < K; k += 64) {
        float m = sum[k] * INVN;
        float v = sumsq[k] * INVN - m * m;
        float sc = g[k] * rsqrtf(v + EPS);
        s_sh[k] = sc;
        t_sh[k] = beta[k] - m * sc;
    }
    __syncthreads();
    float dot = 0.f;
    for (int k = lane; k < K; k += 64) {
        float w = W[(size_t)n * K + k];
        Wf[(size_t)n * K + k] = (__bf16)(w * s_sh[k]);
        dot += w * t_sh[k];
    }
    #pragma unroll
    for (int off = 32; off; off >>= 1) dot += __shfl_down(dot, off);
    if (lane == 0) bf_[n] = b[n] + dot;
}

// ---- fused finalize: one wave per node row.
//  * computes s3,t3 inline per lane from sum3/sq3
//  * F = Y3*s3 + t3  (the 'f' output, fp32)
//  * node_update = s3 * mean_k(Y3[neigh]) + t3  (BN after mean; linear)
__global__ __launch_bounds__(256)
void finalize_k(const __bf16* __restrict__ Y3, const int* __restrict__ idx,
                const float* __restrict__ sum3, const float* __restrict__ sq3,
                const float* __restrict__ g3, const float* __restrict__ be3,
                float* __restrict__ F, float* __restrict__ out, int N)
{
    const int row = blockIdx.x * 4 + (threadIdx.x >> 6);  // one row per wave
    if (row >= N) return;
    const int lane = threadIdx.x & 63;
    const int c = lane * 2;

    const float2 sm = *(const float2*)(sum3 + c);
    const float2 sq = *(const float2*)(sq3 + c);
    const float2 gg = *(const float2*)(g3 + c);
    const float2 bb = *(const float2*)(be3 + c);
    const float m0 = sm.x * INVN, m1 = sm.y * INVN;
    const float v0 = sq.x * INVN - m0 * m0, v1 = sq.y * INVN - m1 * m1;
    const float s0 = gg.x * rsqrtf(v0 + EPS), s1 = gg.y * rsqrtf(v1 + EPS);
    const float t0 = bb.x - m0 * s0, t1 = bb.y - m1 * s1;

    bf16x2 own = *(const bf16x2*)(Y3 + (size_t)row * 128 + c);
    float2 f;
    f.x = (float)own[0] * s0 + t0;
    f.y = (float)own[1] * s1 + t1;
    *(float2*)(F + (size_t)row * 128 + c) = f;

    const int* ib = idx + (size_t)row * 16;
    float a0 = 0.f, a1 = 0.f;
    #pragma unroll
    for (int k = 0; k < 16; ++k) {
        const int j = ib[k];  // wave-uniform -> scalar load
        bf16x2 v = *(const bf16x2*)(Y3 + (size_t)j * 128 + c);
        a0 += (float)v[0];
        a1 += (float)v[1];
    }
    float2 o;
    o.x = a0 * 0.0625f * s0 + t0;
    o.y = a1 * 0.0625f * s1 + t1;
    *(float2*)(out + (size_t)row * 128 + c) = o;
}

extern "C" void kernel_launch(void* const* d_in, const int* in_sizes, int n_in,
                              void* d_out, int out_size, void* d_ws, size_t ws_size,
                              hipStream_t stream)
{
    const float* X   = (const float*)d_in[0];
    const int*   idx = (const int*)d_in[1];
    // d_in[2] = prob_retained (unused, ==1)
    const float* W1  = (const float*)d_in[3];
    const float* b1  = (const float*)d_in[4];
    const float* g1  = (const float*)d_in[5];
    const float* be1 = (const float*)d_in[6];
    const float* W2  = (const float*)d_in[7];
    const float* b2  = (const float*)d_in[8];
    const float* g2  = (const float*)d_in[9];
    const float* be2 = (const float*)d_in[10];
    const float* W3  = (const float*)d_in[11];
    const float* b3  = (const float*)d_in[12];
    const float* g3  = (const float*)d_in[13];
    const float* be3 = (const float*)d_in[14];

    char* ws = (char*)d_ws;
    float* sum1 = (float*)(ws + 0);
    float* sq1  = (float*)(ws + 1024);
    float* sum2 = (float*)(ws + 2048);
    float* sq2  = (float*)(ws + 3072);
    float* sum3 = (float*)(ws + 4096);
    float* sq3  = (float*)(ws + 4608);
    float* b2f  = (float*)(ws + 10240);
    float* b3f  = (float*)(ws + 11264);
    __bf16* W2f = (__bf16*)(ws + 13312);            // 256*256*2 = 131072 B
    __bf16* W3f = (__bf16*)(ws + 144384);           // 128*256*2 = 65536 B
    __bf16* Y1  = (__bf16*)(ws + (1 << 20));                   // [N,256] bf16 51.2 MB
    __bf16* Y2  = (__bf16*)(ws + (1 << 20) + 51200000);        // [N,256] bf16 51.2 MB
    __bf16* Y3  = Y1;  // [N,128]; Y1 dead after gemm2 (gemm3 reads only Y2)

    float* out_nu = (float*)d_out;                  // node_update [N,128] fp32
    float* F      = out_nu + (size_t)NROWS * 128;   // f [N,128] fp32

    hipMemsetAsync(d_ws, 0, 5120, stream);  // zero sum/sumsq accumulators

    // layer 1: X[100000,128] @ W1[256,128]^T (fp32 converted inline)
    // pinned W-frags; bounds(256,5) -> 5 blocks/CU, grid 640x2 = exactly resident
    gemm_stream<128, 2, 4, 5, 256, true><<<dim3(640, 2), 256, 0, stream>>>(
        nullptr, X, nullptr, W1, b1, Y1, sum1, sq1);
    fold_stats_k<<<256, 64, 0, stream>>>(sum1, sq1, g1, be1, W2, b2, W2f, b2f, 256);

    // layer 2: Y1[100000,256] @ W2'[256,256]^T -> Y2
    // bounds(256,3) -> 3 blocks/CU, grid 384x2 = exactly resident
    gemm_stream<256, 2, 4, 3, 256, false><<<dim3(384, 2), 256, 0, stream>>>(
        Y1, nullptr, W2f, nullptr, b2f, Y2, sum2, sq2);
    fold_stats_k<<<128, 64, 0, stream>>>(sum2, sq2, g2, be2, W3, b3, W3f, b3f, 256);

    // layer 3: Y2[100000,256] @ W3'[128,256]^T -> raw Y3 (pre-BN) into Y1 region
    gemm_stream<256, 2, 4, 3, 128, false><<<dim3(768, 1), 256, 0, stream>>>(
        Y2, nullptr, W3f, nullptr, b3f, Y3, sum3, sq3);

    // fused: stats3 + f-output + neighbor-mean
    finalize_k<<<25000, 256, 0, stream>>>(Y3, idx, sum3, sq3, g3, be3, F, out_nu, NROWS);
}

// Round 6
// 398.016 us; speedup vs baseline: 1.0002x; 1.0002x over previous
//
#include <hip/hip_runtime.h>
#include <hip/hip_bf16.h>

typedef __bf16 bf16x8 __attribute__((ext_vector_type(8)));
typedef __bf16 bf16x2 __attribute__((ext_vector_type(2)));
typedef float f32x4 __attribute__((ext_vector_type(4)));

#define NROWS 100000
#define NSTRIPS 6250   // 100000 / 16, exact
#define EPS 1e-5f
#define SLOPE 0.2f
#define INVN 1e-5f     // 1.0f / 100000

__device__ __forceinline__ bf16x8 cvt8(const float* s) {
    float4 x0 = *(const float4*)s, x1 = *(const float4*)(s + 4);
    bf16x8 o;
    o[0] = (__bf16)x0.x; o[1] = (__bf16)x0.y; o[2] = (__bf16)x0.z; o[3] = (__bf16)x0.w;
    o[4] = (__bf16)x1.x; o[5] = (__bf16)x1.y; o[6] = (__bf16)x1.z; o[7] = (__bf16)x1.w;
    return o;
}

// ---- streaming GEMM: Y = LeakyReLU(A @ W^T + bias), + column sum/sumsq --------
// Round-6 diagnosis: VGPR_Count=40 (r3/r4) proves W-fragments were NEVER
// register-resident -- the compiler sinks the W loads into the strip loop, so
// every iteration re-reads the block's full W slice (128 KB) from L1/L2:
// ~800 MB of L2 traffic per gemm dispatch. Invisible to FETCH_SIZE (L2-hit),
// explains why extra occupancy HURT (more waves contending on the same L2
// lines) and why A-prefetch was neutral.
// Fix: stage W (bf16) into LDS once per block; per-iteration W reads become
// ds_read_b128 -- no L2 round trip. XOR-swizzle (byte ^= (col&7)<<4) kills the
// 512B/256B-row 16-way bank conflict; BOTH sides are plain source-level LDS
// accesses (round 5's global_load_lds+swizzle correctness trap avoided).
// A-path / MFMA / store / sums identical to the r0-r4 passing lineage.
// A-frag: lane reads A[row0+l16][ks*32+quad*8 ..+8]. C/D: col=l16, row=quad*4+r.
template <int KT, int NI, int WAVES, int MINW, int NTOT, bool F32IN>
__global__ __launch_bounds__(WAVES * 64, MINW)
void gemm_wlds(const __bf16* __restrict__ A, const float* __restrict__ A32,
               const __bf16* __restrict__ W, const float* __restrict__ W32,
               const float* __restrict__ bias, __bf16* __restrict__ Y,
               float* __restrict__ sum, float* __restrict__ sumsq)
{
    constexpr int KS = KT / 32;
    constexpr int NC = WAVES * NI * 16;    // cols per block
    constexpr int NTHR = WAVES * 64;
    constexpr int KC8 = KT / 8;            // 16B chunks per row
    // swizzled W tile: element (c,k) at byte c*(KT*2) + ((k*2) ^ ((c&7)<<4))
    __shared__ __align__(16) char Wsh[NC * KT * 2];   // <= 64 KB

    const int tid = threadIdx.x;
    const int wave = tid >> 6, lane = tid & 63;
    const int quad = lane >> 4, l16 = lane & 15;
    const int cb = blockIdx.y * NC;        // block's first (global) column
    const int c0 = wave * (NI * 16);       // wave's first column (block-local)

    // ---- stage W slice -> LDS (bf16), coalesced global reads, swizzled writes
    for (int e = tid; e < NC * KC8; e += NTHR) {
        int c  = e / KC8;                  // block-local col
        int kc = e % KC8;                  // 8-element k-chunk
        int gcol = cb + c;
        bf16x8 v;
        if constexpr (F32IN) v = cvt8(W32 + (size_t)gcol * KT + kc * 8);
        else                 v = *(const bf16x8*)(W + (size_t)gcol * KT + kc * 8);
        *(bf16x8*)(Wsh + c * (KT * 2) + ((kc * 16) ^ ((c & 7) << 4))) = v;
    }
    __syncthreads();

    float bcol[NI];
    #pragma unroll
    for (int ni = 0; ni < NI; ++ni) bcol[ni] = bias[cb + c0 + ni * 16 + l16];

    float csum[NI] = {}, csq[NI] = {};

    for (int s = blockIdx.x; s < NSTRIPS; s += gridDim.x) {
        int row0 = s * 16;
        bf16x8 afrag[KS];
        #pragma unroll
        for (int ks = 0; ks < KS; ++ks) {
            int k = ks * 32 + quad * 8;
            if constexpr (F32IN) afrag[ks] = cvt8(A32 + (size_t)(row0 + l16) * KT + k);
            else                 afrag[ks] = *(const bf16x8*)(A + (size_t)(row0 + l16) * KT + k);
        }
        f32x4 acc[NI] = {};
        #pragma unroll
        for (int ks = 0; ks < KS; ++ks) {
            const int kb = (ks * 32 + quad * 8) * 2;   // byte offset of k-chunk
            #pragma unroll
            for (int ni = 0; ni < NI; ++ni) {
                const int c = c0 + ni * 16 + l16;      // block-local col
                bf16x8 bfrag = *(const bf16x8*)(Wsh + c * (KT * 2) + (kb ^ ((c & 7) << 4)));
                acc[ni] = __builtin_amdgcn_mfma_f32_16x16x32_bf16(
                    afrag[ks], bfrag, acc[ni], 0, 0, 0);
            }
        }

        #pragma unroll
        for (int ni = 0; ni < NI; ++ni) {
            int col = cb + c0 + ni * 16 + l16;
            #pragma unroll
            for (int r = 0; r < 4; ++r) {
                float y = acc[ni][r] + bcol[ni];
                y = (y > 0.f) ? y : SLOPE * y;
                Y[(size_t)(row0 + quad * 4 + r) * NTOT + col] = (__bf16)y;
                csum[ni] += y;
                csq[ni]  += y * y;
            }
        }
    }

    #pragma unroll
    for (int ni = 0; ni < NI; ++ni) {
        float s = csum[ni], q = csq[ni];
        s += __shfl_xor(s, 16); s += __shfl_xor(s, 32);
        q += __shfl_xor(q, 16); q += __shfl_xor(q, 32);
        if (quad == 0) {
            int col = cb + c0 + ni * 16 + l16;
            atomicAdd(&sum[col], s);
            atomicAdd(&sumsq[col], q);
        }
    }
}

// ---- fused stats + fold: recompute s,t from column sums, fold BN into next W.
__global__ void fold_stats_k(const float* __restrict__ sum, const float* __restrict__ sumsq,
                             const float* __restrict__ g, const float* __restrict__ beta,
                             const float* __restrict__ W, const float* __restrict__ b,
                             __bf16* __restrict__ Wf, float* __restrict__ bf_, int K)
{
    __shared__ float s_sh[256], t_sh[256];
    const int n = blockIdx.x, lane = threadIdx.x;  // 64 threads = 1 wave
    for (int k = lane; k < K; k += 64) {
        float m = sum[k] * INVN;
        float v = sumsq[k] * INVN - m * m;
        float sc = g[k] * rsqrtf(v + EPS);
        s_sh[k] = sc;
        t_sh[k] = beta[k] - m * sc;
    }
    __syncthreads();
    float dot = 0.f;
    for (int k = lane; k < K; k += 64) {
        float w = W[(size_t)n * K + k];
        Wf[(size_t)n * K + k] = (__bf16)(w * s_sh[k]);
        dot += w * t_sh[k];
    }
    #pragma unroll
    for (int off = 32; off; off >>= 1) dot += __shfl_down(dot, off);
    if (lane == 0) bf_[n] = b[n] + dot;
}

// ---- fused finalize: stats3 inline + F output + neighbor-mean + BN-after-mean.
__global__ __launch_bounds__(256)
void finalize_k(const __bf16* __restrict__ Y3, const int* __restrict__ idx,
                const float* __restrict__ sum3, const float* __restrict__ sq3,
                const float* __restrict__ g3, const float* __restrict__ be3,
                float* __restrict__ F, float* __restrict__ out, int N)
{
    const int row = blockIdx.x * 4 + (threadIdx.x >> 6);  // one row per wave
    if (row >= N) return;
    const int lane = threadIdx.x & 63;
    const int c = lane * 2;

    const float2 sm = *(const float2*)(sum3 + c);
    const float2 sq = *(const float2*)(sq3 + c);
    const float2 gg = *(const float2*)(g3 + c);
    const float2 bb = *(const float2*)(be3 + c);
    const float m0 = sm.x * INVN, m1 = sm.y * INVN;
    const float v0 = sq.x * INVN - m0 * m0, v1 = sq.y * INVN - m1 * m1;
    const float s0 = gg.x * rsqrtf(v0 + EPS), s1 = gg.y * rsqrtf(v1 + EPS);
    const float t0 = bb.x - m0 * s0, t1 = bb.y - m1 * s1;

    bf16x2 own = *(const bf16x2*)(Y3 + (size_t)row * 128 + c);
    float2 f;
    f.x = (float)own[0] * s0 + t0;
    f.y = (float)own[1] * s1 + t1;
    *(float2*)(F + (size_t)row * 128 + c) = f;

    const int* ib = idx + (size_t)row * 16;
    float a0 = 0.f, a1 = 0.f;
    #pragma unroll
    for (int k = 0; k < 16; ++k) {
        const int j = ib[k];  // wave-uniform -> scalar load
        bf16x2 v = *(const bf16x2*)(Y3 + (size_t)j * 128 + c);
        a0 += (float)v[0];
        a1 += (float)v[1];
    }
    float2 o;
    o.x = a0 * 0.0625f * s0 + t0;
    o.y = a1 * 0.0625f * s1 + t1;
    *(float2*)(out + (size_t)row * 128 + c) = o;
}

extern "C" void kernel_launch(void* const* d_in, const int* in_sizes, int n_in,
                              void* d_out, int out_size, void* d_ws, size_t ws_size,
                              hipStream_t stream)
{
    const float* X   = (const float*)d_in[0];
    const int*   idx = (const int*)d_in[1];
    // d_in[2] = prob_retained (unused, ==1)
    const float* W1  = (const float*)d_in[3];
    const float* b1  = (const float*)d_in[4];
    const float* g1  = (const float*)d_in[5];
    const float* be1 = (const float*)d_in[6];
    const float* W2  = (const float*)d_in[7];
    const float* b2  = (const float*)d_in[8];
    const float* g2  = (const float*)d_in[9];
    const float* be2 = (const float*)d_in[10];
    const float* W3  = (const float*)d_in[11];
    const float* b3  = (const float*)d_in[12];
    const float* g3  = (const float*)d_in[13];
    const float* be3 = (const float*)d_in[14];

    char* ws = (char*)d_ws;
    float* sum1 = (float*)(ws + 0);
    float* sq1  = (float*)(ws + 1024);
    float* sum2 = (float*)(ws + 2048);
    float* sq2  = (float*)(ws + 3072);
    float* sum3 = (float*)(ws + 4096);
    float* sq3  = (float*)(ws + 4608);
    float* b2f  = (float*)(ws + 10240);
    float* b3f  = (float*)(ws + 11264);
    __bf16* W2f = (__bf16*)(ws + 13312);            // 256*256*2 = 131072 B
    __bf16* W3f = (__bf16*)(ws + 144384);           // 128*256*2 = 65536 B
    __bf16* Y1  = (__bf16*)(ws + (1 << 20));                   // [N,256] bf16 51.2 MB
    __bf16* Y2  = (__bf16*)(ws + (1 << 20) + 51200000);        // [N,256] bf16 51.2 MB
    __bf16* Y3  = Y1;  // [N,128]; Y1 dead after gemm2 (gemm3 reads only Y2)

    float* out_nu = (float*)d_out;                  // node_update [N,128] fp32
    float* F      = out_nu + (size_t)NROWS * 128;   // f [N,128] fp32

    hipMemsetAsync(d_ws, 0, 5120, stream);  // zero sum/sumsq accumulators

    // layer 1: X[100000,128] fp32 @ W1[256,128]^T
    // 8-wave blocks, NC=256 (y=1), LDS 64 KB -> 2 blocks/CU = 16 waves/CU
    gemm_wlds<128, 2, 8, 4, 256, true><<<dim3(512, 1), 512, 0, stream>>>(
        nullptr, X, nullptr, W1, b1, Y1, sum1, sq1);
    fold_stats_k<<<256, 64, 0, stream>>>(sum1, sq1, g1, be1, W2, b2, W2f, b2f, 256);

    // layer 2: Y1[100000,256] bf16 @ W2'[256,256]^T -> Y2
    // 4-wave blocks, NC=128 (y=2), LDS 64 KB -> 2 blocks/CU = 8 waves/CU
    gemm_wlds<256, 2, 4, 2, 256, false><<<dim3(512, 2), 256, 0, stream>>>(
        Y1, nullptr, W2f, nullptr, b2f, Y2, sum2, sq2);
    fold_stats_k<<<128, 64, 0, stream>>>(sum2, sq2, g2, be2, W3, b3, W3f, b3f, 256);

    // layer 3: Y2[100000,256] bf16 @ W3'[128,256]^T -> raw Y3 (pre-BN), y=1
    gemm_wlds<256, 2, 4, 2, 128, false><<<dim3(512, 1), 256, 0, stream>>>(
        Y2, nullptr, W3f, nullptr, b3f, Y3, sum3, sq3);

    // fused: stats3 + f-output + neighbor-mean
    finalize_k<<<25000, 256, 0, stream>>>(Y3, idx, sum3, sq3, g3, be3, F, out_nu, NROWS);
}